// Round 3
// baseline (1219.877 us; speedup 1.0000x reference)
//
#include <hip/hip_runtime.h>
#include <hip/hip_bf16.h>
#include <cstdint>
#include <cstddef>

// ---------------- problem constants ----------------
#define B_    4
#define N_    2048
#define C_    1024
#define H_    16
#define D_    64
#define TOK   (B_ * N_)          // 8192
#define MLP_  4096
#define INNER_   2730
#define INNER_P  2752            // padded to 32
#define NG_      5460            // 2*INNER
#define NG_P     5504            // padded to 128

typedef unsigned short u16;
typedef __attribute__((ext_vector_type(4))) float f32x4;
typedef __attribute__((ext_vector_type(8))) short bf16x8;

#define MFMA_BF16(a, b, c) __builtin_amdgcn_mfma_f32_16x16x32_bf16((a), (b), (c), 0, 0, 0)

__device__ __forceinline__ u16 f2bf(float f) {
    union { float f; unsigned u; } v; v.f = f;
    unsigned r = v.u + 0x7FFFu + ((v.u >> 16) & 1u);
    return (u16)(r >> 16);
}
__device__ __forceinline__ float bf2f(u16 u) {
    union { float f; unsigned u; } v; v.u = ((unsigned)u) << 16; return v.f;
}
__device__ __forceinline__ ushort4 bf4(float a, float b, float c, float d) {
    ushort4 o; o.x = f2bf(a); o.y = f2bf(b); o.z = f2bf(c); o.w = f2bf(d); return o;
}

// ---------------- weight transpose + convert: W (K x N) f32 -> Wt (Np x Kp) bf16, zero-padded
__global__ __launch_bounds__(256)
void tb_transpose_bf16(const float* __restrict__ W, u16* __restrict__ Wt,
                       int K, int N, int Kp, int Np) {
    __shared__ float tile[32][33];
    const int k0 = blockIdx.x * 32, n0 = blockIdx.y * 32;
    const int t = threadIdx.x;
    const int r = t >> 3, c0 = (t & 7) * 4;
#pragma unroll
    for (int i = 0; i < 4; i++) {
        int k = k0 + r, n = n0 + c0 + i;
        tile[r][c0 + i] = (k < K && n < N) ? W[(size_t)k * N + n] : 0.f;
    }
    __syncthreads();
#pragma unroll
    for (int i = 0; i < 4; i++) {
        Wt[(size_t)(n0 + r) * Kp + k0 + c0 + i] = f2bf(tile[c0 + i][r]);
    }
}

// ---------------- Wm_in transpose with GLU row-interleave:
// Wt row 2i   = Wm_in col i        (vv), i<INNER else 0
// Wt row 2i+1 = Wm_in col INNER+i  (g),  i<INNER else 0
__global__ __launch_bounds__(256)
void tb_transpose_glu(const float* __restrict__ W, u16* __restrict__ Wt) {
    __shared__ float tv[32][17], tg[32][17];
    const int k0 = blockIdx.x * 32, r0 = blockIdx.y * 32;
    const int s0 = r0 >> 1;
    const int t = threadIdx.x;
    const int kk = t >> 3, j0 = (t & 7) * 2;
#pragma unroll
    for (int i = 0; i < 2; i++) {
        int j = j0 + i, k = k0 + kk;
        int cV = s0 + j, cG = INNER_ + s0 + j;
        tv[kk][j] = (cV < INNER_) ? W[(size_t)k * NG_ + cV] : 0.f;
        tg[kk][j] = (cG < NG_)    ? W[(size_t)k * NG_ + cG] : 0.f;
    }
    __syncthreads();
    const int r = t >> 3, c0 = (t & 7) * 4;
#pragma unroll
    for (int i = 0; i < 4; i++) {
        int k = c0 + i;
        float v = (r & 1) ? tg[k][r >> 1] : tv[k][r >> 1];
        Wt[(size_t)(r0 + r) * 1024 + k0 + k] = f2bf(v);
    }
}

// ---------------- f32 -> bf16 convert (vectorized, grid-stride over groups of 4)
__global__ __launch_bounds__(256)
void tb_conv_bf16(const float* __restrict__ in, u16* __restrict__ out, int n4) {
    int i = blockIdx.x * 256 + threadIdx.x;
    const int stride = gridDim.x * 256;
    for (; i < n4; i += stride) {
        f32x4 v = ((const f32x4*)in)[i];
        ((ushort4*)out)[i] = bf4(v.x, v.y, v.z, v.w);
    }
}

// ---------------- permuted GLU bias: bp[2i]=b[i], bp[2i+1]=b[INNER+i], pad 0
__global__ __launch_bounds__(256)
void tb_bias_glu(const float* __restrict__ b, float* __restrict__ bp) {
    int r = blockIdx.x * 256 + threadIdx.x;
    if (r < NG_P) {
        int i = r >> 1;
        float v = 0.f;
        if (i < INNER_) v = (r & 1) ? b[INNER_ + i] : b[i];
        bp[r] = v;
    }
}

// ---------------- GEMM: out(M x N) = A(M x K, bf16) @ Bt(N x K, bf16)^T + bias
// EPI 1: f32 out + add       EPI 3: bf16 out
// EPI 4: GLU pairs (even col = vv, odd = g) -> silu(g)*vv at col>>1, bf16
// EPI 5: silu -> bf16
template <int EPI>
__global__ __launch_bounds__(256)
void tb_gemm(const u16* __restrict__ A, const u16* __restrict__ Bt,
             const float* __restrict__ bias, const float* add,
             float* outf, u16* outb,
             int M, int N, int K, int lda, int ldb, int ldc) {
    __shared__ u16 As[128 * 32];
    __shared__ u16 Bs[128 * 32];
    const int tid = threadIdx.x;
    const int l = tid & 63, w = tid >> 6;
    const int wr = w >> 1, wc = w & 1;
    const int fr = l & 15, fq = l >> 4;
    const int ntn = N >> 7;
    const int bm0 = (blockIdx.x / ntn) << 7;
    const int bn0 = (blockIdx.x % ntn) << 7;

    const int c0 = tid, c1 = tid + 256;
    const int ar0 = c0 >> 2, ak0 = (c0 & 3) * 8;
    const int ar1 = c1 >> 2, ak1 = (c1 & 3) * 8;

    const u16* Ab = A + (size_t)bm0 * lda;
    const u16* Bb = Bt + (size_t)bn0 * ldb;

    f32x4 acc[4][4] = {};

    bf16x8 ra0 = *(const bf16x8*)(Ab + (size_t)ar0 * lda + ak0);
    bf16x8 ra1 = *(const bf16x8*)(Ab + (size_t)ar1 * lda + ak1);
    bf16x8 rb0 = *(const bf16x8*)(Bb + (size_t)ar0 * ldb + ak0);
    bf16x8 rb1 = *(const bf16x8*)(Bb + (size_t)ar1 * ldb + ak1);

    const int nk = K >> 5;
    for (int kt = 0; kt < nk; kt++) {
        __syncthreads();
        ((bf16x8*)As)[c0] = ra0; ((bf16x8*)As)[c1] = ra1;
        ((bf16x8*)Bs)[c0] = rb0; ((bf16x8*)Bs)[c1] = rb1;
        __syncthreads();
        if (kt + 1 < nk) {
            const int k0 = (kt + 1) << 5;
            ra0 = *(const bf16x8*)(Ab + (size_t)ar0 * lda + k0 + ak0);
            ra1 = *(const bf16x8*)(Ab + (size_t)ar1 * lda + k0 + ak1);
            rb0 = *(const bf16x8*)(Bb + (size_t)ar0 * ldb + k0 + ak0);
            rb1 = *(const bf16x8*)(Bb + (size_t)ar1 * ldb + k0 + ak1);
        }
        bf16x8 af[4], bfr[4];
#pragma unroll
        for (int mi = 0; mi < 4; mi++)
            af[mi] = ((const bf16x8*)As)[(wr * 64 + mi * 16 + fr) * 4 + fq];
#pragma unroll
        for (int ni = 0; ni < 4; ni++)
            bfr[ni] = ((const bf16x8*)Bs)[(wc * 64 + ni * 16 + fr) * 4 + fq];
#pragma unroll
        for (int mi = 0; mi < 4; mi++)
#pragma unroll
            for (int ni = 0; ni < 4; ni++)
                acc[mi][ni] = MFMA_BF16(af[mi], bfr[ni], acc[mi][ni]);
    }

#pragma unroll
    for (int mi = 0; mi < 4; mi++) {
#pragma unroll
        for (int ni = 0; ni < 4; ni++) {
            const int row0 = bm0 + wr * 64 + mi * 16 + fq * 4;
            const int col  = bn0 + wc * 64 + ni * 16 + fr;
            const float bc = bias[col];
#pragma unroll
            for (int j = 0; j < 4; j++) {
                float v = acc[mi][ni][j] + bc;
                if constexpr (EPI == 1) {
                    size_t oi = (size_t)(row0 + j) * ldc + col;
                    outf[oi] = v + add[oi];
                } else if constexpr (EPI == 3) {
                    outb[(size_t)(row0 + j) * ldc + col] = f2bf(v);
                } else if constexpr (EPI == 5) {
                    float s = v * (1.f / (1.f + __expf(-v)));
                    outb[(size_t)(row0 + j) * ldc + col] = f2bf(s);
                } else { // EPI == 4: GLU pair fuse
                    float partner = __shfl_xor(v, 1, 64);
                    if ((fr & 1) == 0) {
                        float g = partner;
                        float a = g * (1.f / (1.f + __expf(-g))) * v;
                        outb[(size_t)(row0 + j) * ldc + (col >> 1)] = f2bf(a);
                    }
                }
            }
        }
    }
}

// ---------------- LN over C with AdaLN modulate: xn = LN(x)*lw+lb, *(1+scale)+shift -> bf16
__global__ __launch_bounds__(256)
void tb_ln_mod(const float* __restrict__ x, const u16* __restrict__ se,
               const float* __restrict__ lw, const float* __restrict__ lb,
               u16* __restrict__ xn) {
    const int tok = blockIdx.x;
    const int t = threadIdx.x;
    f32x4 v = ((const f32x4*)(x + (size_t)tok * 1024))[t];
    float s = v.x + v.y + v.z + v.w;
    float ss = v.x * v.x + v.y * v.y + v.z * v.z + v.w * v.w;
#pragma unroll
    for (int m = 1; m < 64; m <<= 1) {
        s += __shfl_xor(s, m, 64);
        ss += __shfl_xor(ss, m, 64);
    }
    __shared__ float sb[4], ssb[4];
    if ((t & 63) == 0) { sb[t >> 6] = s; ssb[t >> 6] = ss; }
    __syncthreads();
    s = sb[0] + sb[1] + sb[2] + sb[3];
    ss = ssb[0] + ssb[1] + ssb[2] + ssb[3];
    const float mu = s * (1.f / 1024.f);
    const float var = ss * (1.f / 1024.f) - mu * mu;
    const float rs = rsqrtf(var + 1e-5f);
    f32x4 w4 = ((const f32x4*)lw)[t];
    f32x4 b4 = ((const f32x4*)lb)[t];
    const u16* ser = se + (size_t)tok * 2048;
    ushort4 scu = ((const ushort4*)ser)[t];
    ushort4 shu = ((const ushort4*)(ser + 1024))[t];
    float y0 = ((v.x - mu) * rs * w4.x + b4.x) * (1.f + bf2f(scu.x)) + bf2f(shu.x);
    float y1 = ((v.y - mu) * rs * w4.y + b4.y) * (1.f + bf2f(scu.y)) + bf2f(shu.y);
    float y2 = ((v.z - mu) * rs * w4.z + b4.z) * (1.f + bf2f(scu.z)) + bf2f(shu.z);
    float y3 = ((v.w - mu) * rs * w4.w + b4.w) * (1.f + bf2f(scu.w)) + bf2f(shu.w);
    ((ushort4*)xn)[(size_t)tok * 256 + t] = bf4(y0, y1, y2, y3);
}

// ---------------- per-head LN of q,k over D=64 + v passthrough, bf16 in (tok,3072) -> bf16 (B,N,H,D)
__global__ __launch_bounds__(256)
void tb_qkv_ln(const u16* __restrict__ qkv,
               const float* __restrict__ qw, const float* __restrict__ qb,
               const float* __restrict__ kw, const float* __restrict__ kb,
               u16* __restrict__ qo, u16* __restrict__ ko, u16* __restrict__ vo) {
    const int tok = blockIdx.x;
    const int t = threadIdx.x;
    const int h = t >> 4, ln16 = t & 15;
    const u16* base = qkv + (size_t)tok * 3072 + h * 64 + ln16 * 4;
    ushort4 qu = *(const ushort4*)(base);
    ushort4 ku = *(const ushort4*)(base + 1024);
    ushort4 vu = *(const ushort4*)(base + 2048);
    float q0 = bf2f(qu.x), q1 = bf2f(qu.y), q2 = bf2f(qu.z), q3 = bf2f(qu.w);
    float k0 = bf2f(ku.x), k1 = bf2f(ku.y), k2 = bf2f(ku.z), k3 = bf2f(ku.w);
    float qs = q0 + q1 + q2 + q3, qss = q0 * q0 + q1 * q1 + q2 * q2 + q3 * q3;
    float ks = k0 + k1 + k2 + k3, kss = k0 * k0 + k1 * k1 + k2 * k2 + k3 * k3;
#pragma unroll
    for (int m = 1; m < 16; m <<= 1) {
        qs += __shfl_xor(qs, m, 64); qss += __shfl_xor(qss, m, 64);
        ks += __shfl_xor(ks, m, 64); kss += __shfl_xor(kss, m, 64);
    }
    const float qmu = qs * (1.f / 64.f), kmu = ks * (1.f / 64.f);
    const float qrs = rsqrtf(qss * (1.f / 64.f) - qmu * qmu + 1e-5f);
    const float krs = rsqrtf(kss * (1.f / 64.f) - kmu * kmu + 1e-5f);
    f32x4 qw4 = ((const f32x4*)qw)[ln16], qb4 = ((const f32x4*)qb)[ln16];
    f32x4 kw4 = ((const f32x4*)kw)[ln16], kb4 = ((const f32x4*)kb)[ln16];
    const size_t oidx = (((size_t)tok * 16 + h) * 64 + ln16 * 4) >> 2;
    ((ushort4*)qo)[oidx] = bf4((q0 - qmu) * qrs * qw4.x + qb4.x, (q1 - qmu) * qrs * qw4.y + qb4.y,
                               (q2 - qmu) * qrs * qw4.z + qb4.z, (q3 - qmu) * qrs * qw4.w + qb4.w);
    ((ushort4*)ko)[oidx] = bf4((k0 - kmu) * krs * kw4.x + kb4.x, (k1 - kmu) * krs * kw4.y + kb4.y,
                               (k2 - kmu) * krs * kw4.z + kb4.z, (k3 - kmu) * krs * kw4.w + kb4.w);
    ((ushort4*)vo)[oidx] = vu;
}

// ---------------- flash attention: q,k,v bf16 (B,N,H,D) -> o bf16 (B,N,H,D)
__global__ __launch_bounds__(256)
void tb_attn(const u16* __restrict__ q, const u16* __restrict__ k,
             const u16* __restrict__ v, u16* __restrict__ o) {
    const int qb = blockIdx.x, bh = blockIdx.y;
    const int b = bh >> 4, h = bh & 15;
    const int t = threadIdx.x, l = t & 63, w = t >> 6;
    const int fr = l & 15, fq = l >> 4;
    __shared__ u16 VT[64 * 72];
    __shared__ u16 P[4][16 * 72];

    const int q0 = qb * 64 + w * 16;
    const u16* qp = q + (size_t)b * N_ * 1024 + h * 64;
    const u16* kp = k + (size_t)b * N_ * 1024 + h * 64;
    const u16* vp = v + (size_t)b * N_ * 1024 + h * 64;

    bf16x8 aq[2];
    aq[0] = *(const bf16x8*)(qp + (size_t)(q0 + fr) * 1024 + fq * 8);
    aq[1] = *(const bf16x8*)(qp + (size_t)(q0 + fr) * 1024 + 32 + fq * 8);

    float m_r[4], l_r[4];
    f32x4 oa[4];
#pragma unroll
    for (int r = 0; r < 4; r++) { m_r[r] = -1e30f; l_r[r] = 0.f; }
#pragma unroll
    for (int c = 0; c < 4; c++) oa[c] = f32x4{0.f, 0.f, 0.f, 0.f};

    for (int kt = 0; kt < N_ / 64; kt++) {
        const int kv0 = kt * 64;
#pragma unroll
        for (int i = 0; i < 16; i++) {
            int lin = i * 256 + t;
            int kvr = lin >> 6, d = lin & 63;
            VT[d * 72 + kvr] = vp[(size_t)(kv0 + kvr) * 1024 + d];
        }
        __syncthreads();
        f32x4 sfr[4];
#pragma unroll
        for (int c = 0; c < 4; c++) {
            bf16x8 bk0 = *(const bf16x8*)(kp + (size_t)(kv0 + c * 16 + fr) * 1024 + fq * 8);
            bf16x8 bk1 = *(const bf16x8*)(kp + (size_t)(kv0 + c * 16 + fr) * 1024 + 32 + fq * 8);
            f32x4 sa = {};
            sa = MFMA_BF16(aq[0], bk0, sa);
            sa = MFMA_BF16(aq[1], bk1, sa);
            sfr[c] = sa * 0.125f;
        }
        float alpha[4];
#pragma unroll
        for (int r = 0; r < 4; r++) {
            float mx = fmaxf(fmaxf(sfr[0][r], sfr[1][r]), fmaxf(sfr[2][r], sfr[3][r]));
#pragma unroll
            for (int mm = 1; mm < 16; mm <<= 1) mx = fmaxf(mx, __shfl_xor(mx, mm, 64));
            float nm = fmaxf(m_r[r], mx);
            alpha[r] = __expf(m_r[r] - nm);
            m_r[r] = nm;
        }
        float rs[4] = {0.f, 0.f, 0.f, 0.f};
#pragma unroll
        for (int c = 0; c < 4; c++) {
#pragma unroll
            for (int r = 0; r < 4; r++) {
                float p = __expf(sfr[c][r] - m_r[r]);
                rs[r] += p;
                P[w][(fq * 4 + r) * 72 + c * 16 + fr] = f2bf(p);
            }
        }
#pragma unroll
        for (int r = 0; r < 4; r++) {
#pragma unroll
            for (int mm = 1; mm < 16; mm <<= 1) rs[r] += __shfl_xor(rs[r], mm, 64);
            l_r[r] = l_r[r] * alpha[r] + rs[r];
        }
#pragma unroll
        for (int c2 = 0; c2 < 4; c2++) {
            oa[c2][0] *= alpha[0]; oa[c2][1] *= alpha[1];
            oa[c2][2] *= alpha[2]; oa[c2][3] *= alpha[3];
        }
#pragma unroll
        for (int kk = 0; kk < 2; kk++) {
            bf16x8 pa = *(const bf16x8*)&P[w][fr * 72 + kk * 32 + fq * 8];
#pragma unroll
            for (int c2 = 0; c2 < 4; c2++) {
                bf16x8 vbb = *(const bf16x8*)&VT[(c2 * 16 + fr) * 72 + kk * 32 + fq * 8];
                oa[c2] = MFMA_BF16(pa, vbb, oa[c2]);
            }
        }
        __syncthreads();
    }
    u16* op = o + (size_t)b * N_ * 1024 + h * 64;
#pragma unroll
    for (int c2 = 0; c2 < 4; c2++)
#pragma unroll
        for (int r = 0; r < 4; r++)
            op[(size_t)(q0 + fq * 4 + r) * 1024 + c2 * 16 + fr] = f2bf(oa[c2][r] / l_r[r]);
}

// ---------------- rms partial reduction over bf16 f: sum f^2 per (b,h) -> rbuf[64]
__global__ __launch_bounds__(256)
void tb_rms_reduce(const u16* __restrict__ f, float* __restrict__ rbuf) {
    const int bid = blockIdx.x;          // 1024 = 64 (b,h) * 16 parts
    const int bh = bid >> 4, part = bid & 15;
    const int b = bh >> 4, h = bh & 15;
    const int t = threadIdx.x;
    const int d = t & 63, nn = t >> 6;
    const u16* fp = f + (size_t)b * N_ * 1024 + h * 64 + d;
    float s = 0.f;
#pragma unroll 4
    for (int i = 0; i < 32; i++) {
        int n = part * 128 + nn + i * 4;
        float v = bf2f(fp[(size_t)n * 1024]);
        s += v * v;
    }
#pragma unroll
    for (int m = 1; m < 64; m <<= 1) s += __shfl_xor(s, m, 64);
    __shared__ float sb[4];
    if ((t & 63) == 0) sb[t >> 6] = s;
    __syncthreads();
    if (t == 0) atomicAdd(&rbuf[bh], sb[0] + sb[1] + sb[2] + sb[3]);
}

// ---------------- gate = tanh(x @ W_g + b_g)  (8192 x 16)
__global__ __launch_bounds__(256)
void tb_gate(const float* __restrict__ x, const float* __restrict__ Wg,
             const float* __restrict__ bg, float* __restrict__ gate) {
    const int tok = blockIdx.x;
    const int t = threadIdx.x;
    const int h = t & 15, part = t >> 4;
    const float* xr = x + (size_t)tok * 1024 + part * 64;
    float s = 0.f;
#pragma unroll 8
    for (int c = 0; c < 64; c++) s += xr[c] * Wg[(size_t)(part * 64 + c) * 16 + h];
    s += __shfl_xor(s, 16, 64);
    s += __shfl_xor(s, 32, 64);
    __shared__ float gb[4][16];
    if ((t & 63) < 16) gb[t >> 6][t & 15] = s;
    __syncthreads();
    if (t < 16) gate[(size_t)tok * 16 + t] = tanhf(gb[0][t] + gb[1][t] + gb[2][t] + gb[3][t] + bg[t]);
}

// ---------------- o_final = (o + gate * f / rms) -> bf16
__global__ __launch_bounds__(256)
void tb_combine(const u16* __restrict__ o, const u16* __restrict__ f,
                const float* __restrict__ gate, const float* __restrict__ rbuf,
                u16* __restrict__ ob) {
    const int i = blockIdx.x * 256 + threadIdx.x;   // over TOK*1024/4 groups of 4
    const int idx4 = i * 4;
    const int h = (idx4 >> 6) & 15;
    const int tok = idx4 >> 10;
    const int b = idx4 >> 21;
    const float g = gate[(size_t)tok * 16 + h];
    float r = rbuf[(b << 4) + h];
    r = fmaxf(sqrtf(r * (1.f / 131072.f)), 1e-6f);
    const float inv = g / r;
    ushort4 ou = ((const ushort4*)o)[i];
    ushort4 fu = ((const ushort4*)f)[i];
    float r0 = bf2f(ou.x) + bf2f(fu.x) * inv;
    float r1 = bf2f(ou.y) + bf2f(fu.y) * inv;
    float r2 = bf2f(ou.z) + bf2f(fu.z) * inv;
    float r3 = bf2f(ou.w) + bf2f(fu.w) * inv;
    ((ushort4*)ob)[i] = bf4(r0, r1, r2, r3);
}

// =====================================================================
extern "C" void kernel_launch(void* const* d_in, const int* in_sizes, int n_in,
                              void* d_out, int out_size, void* d_ws, size_t ws_size,
                              hipStream_t stream) {
    const float* x      = (const float*)d_in[0];
    const float* emb    = (const float*)d_in[1];
    const float* W_emb  = (const float*)d_in[2];
    const float* b_emb  = (const float*)d_in[3];
    const float* ln_w   = (const float*)d_in[4];
    const float* ln_b   = (const float*)d_in[5];
    const float* W_f    = (const float*)d_in[6];
    const float* b_f    = (const float*)d_in[7];
    const float* qn_w   = (const float*)d_in[8];
    const float* qn_b   = (const float*)d_in[9];
    const float* kn_w   = (const float*)d_in[10];
    const float* kn_b   = (const float*)d_in[11];
    const float* W_ao   = (const float*)d_in[12];
    const float* b_ao   = (const float*)d_in[13];
    const float* W_mo   = (const float*)d_in[14];
    const float* b_mo   = (const float*)d_in[15];
    const float* Wm_in  = (const float*)d_in[16];
    const float* bm_in  = (const float*)d_in[17];
    const float* Wm_out = (const float*)d_in[18];
    const float* bm_out = (const float*)d_in[19];
    const float* W_g    = (const float*)d_in[20];
    const float* b_g    = (const float*)d_in[21];
    float* out = (float*)d_out;
    char* ws = (char*)d_ws;
    (void)ws_size; (void)n_in; (void)in_sizes; (void)out_size;

    // ---- workspace layout (bytes, ~181 MB total) ----
    size_t off = 0;
    auto alloc = [&](size_t bytes) { size_t o = off; off += (bytes + 255) & ~(size_t)255; return o; };
    const size_t oWfT    = alloc((size_t)7168 * 1024 * 2);   // [prep -> 14a]
    const size_t oWminT  = alloc((size_t)NG_P * 1024 * 2);   // [prep -> 7]
    const size_t oWmoutT = alloc((size_t)1024 * INNER_P * 2);// [prep -> 9]
    const size_t oWaoT   = alloc((size_t)1024 * 1024 * 2);   // [prep -> 13]
    const size_t oWmoT   = alloc((size_t)1024 * 4096 * 2);   // [prep -> 14b]
    const size_t oWembT  = alloc((size_t)2048 * 1024 * 2);   // [prep -> 2]  then obuf
    const size_t oEmbB   = alloc((size_t)TOK * 1024 * 2);    // [prep -> 2]  (obuf spans WembT+EmbB)
    // oY: se bf16 [2->3], qkv [4->5], act [7->9]; sm spans oY+oZql [14a->14b]
    const size_t oY      = alloc((size_t)TOK * 3072 * 2);
    const size_t oZql    = alloc((size_t)TOK * 1024 * 2);    // ql [5 -> 7]
    const size_t oZkl    = alloc((size_t)TOK * 1024 * 2);    // kl [5 -> 6], fbuf [9 -> 12]
    const size_t oZvb    = alloc((size_t)TOK * 1024 * 2);    // vb [5 -> 6], ob [12 -> 13]
    const size_t oXN     = alloc((size_t)TOK * 1024 * 2);    // xn [3 -> 14a]
    const size_t oBias   = alloc((size_t)NG_P * 4);
    const size_t oGate   = alloc((size_t)TOK * 16 * 4);
    const size_t oRms    = alloc((size_t)64 * 4);

    u16* WfT    = (u16*)(ws + oWfT);
    u16* WminT  = (u16*)(ws + oWminT);
    u16* WmoutT = (u16*)(ws + oWmoutT);
    u16* WaoT   = (u16*)(ws + oWaoT);
    u16* WmoT   = (u16*)(ws + oWmoT);
    u16* WembT  = (u16*)(ws + oWembT);
    u16* embB   = (u16*)(ws + oEmbB);
    u16* se     = (u16*)(ws + oY);          // 33.6 MB, dead before qkv is written
    u16* qkv    = (u16*)(ws + oY);
    u16* act    = (u16*)(ws + oY);
    u16* sm     = (u16*)(ws + oY);          // 64 MiB = oY(48) + oZql(16), both dead by 14a
    u16* ql     = (u16*)(ws + oZql);
    u16* kl     = (u16*)(ws + oZkl);
    u16* fbuf   = (u16*)(ws + oZkl);
    u16* vb     = (u16*)(ws + oZvb);
    u16* ob     = (u16*)(ws + oZvb);
    u16* obuf   = (u16*)(ws + oWembT);      // 16 MiB inside WembT+EmbB (20 MiB)
    u16* xn     = (u16*)(ws + oXN);
    float* biasP = (float*)(ws + oBias);
    float* gate = (float*)(ws + oGate);
    float* rms  = (float*)(ws + oRms);

    // ---- 1. weight prep ----
    hipLaunchKernelGGL(tb_transpose_bf16, dim3(32, 64),  dim3(256), 0, stream, W_emb,  WembT,  1024, 2048, 1024, 2048);
    hipLaunchKernelGGL(tb_transpose_bf16, dim3(32, 224), dim3(256), 0, stream, W_f,    WfT,    1024, 7168, 1024, 7168);
    hipLaunchKernelGGL(tb_transpose_glu,  dim3(32, 172), dim3(256), 0, stream, Wm_in,  WminT);
    hipLaunchKernelGGL(tb_transpose_bf16, dim3(86, 32),  dim3(256), 0, stream, Wm_out, WmoutT, INNER_, 1024, INNER_P, 1024);
    hipLaunchKernelGGL(tb_transpose_bf16, dim3(32, 32),  dim3(256), 0, stream, W_ao,   WaoT,   1024, 1024, 1024, 1024);
    hipLaunchKernelGGL(tb_transpose_bf16, dim3(128, 32), dim3(256), 0, stream, W_mo,   WmoT,   4096, 1024, 4096, 1024);
    hipLaunchKernelGGL(tb_conv_bf16, dim3(4096), dim3(256), 0, stream, emb, embB, TOK * 1024 / 4);
    hipLaunchKernelGGL(tb_bias_glu, dim3((NG_P + 255) / 256), dim3(256), 0, stream, bm_in, biasP);
    hipMemsetAsync(rms, 0, 64 * sizeof(float), stream);

    // ---- 2. se = emb @ W_emb + b_emb  (bf16 out) ----
    hipLaunchKernelGGL((tb_gemm<3>), dim3(64 * 16), dim3(256), 0, stream,
                       embB, WembT, b_emb, nullptr, nullptr, se, TOK, 2048, 1024, 1024, 1024, 2048);
    // ---- 3. xn = LN(x)*(1+scale)+shift ----
    hipLaunchKernelGGL(tb_ln_mod, dim3(TOK), dim3(256), 0, stream, x, se, ln_w, ln_b, xn);
    // ---- 4. qkv = xn @ W_f[:, :3072] + b_f[:3072]  (bf16 out) ----
    hipLaunchKernelGGL((tb_gemm<3>), dim3(64 * 24), dim3(256), 0, stream,
                       xn, WfT, b_f, nullptr, nullptr, qkv, TOK, 3072, 1024, 1024, 1024, 3072);
    // ---- 5. q/k LN per head, v copy ----
    hipLaunchKernelGGL(tb_qkv_ln, dim3(TOK), dim3(256), 0, stream, qkv, qn_w, qn_b, kn_w, kn_b, ql, kl, vb);
    // ---- 6. attention -> obuf bf16 ----
    hipLaunchKernelGGL(tb_attn, dim3(N_ / 64, B_ * H_), dim3(256), 0, stream, ql, kl, vb, obuf);
    // ---- 7. act = silu(g)*vv fused into GLU gemm (ql @ WminT_perm) ----
    hipLaunchKernelGGL((tb_gemm<4>), dim3(64 * 43), dim3(256), 0, stream,
                       ql, WminT, biasP, nullptr, nullptr, act, TOK, NG_P, 1024, 1024, 1024, INNER_P);
    // ---- 9. f = act @ Wm_out + bm_out  (bf16 out) ----
    hipLaunchKernelGGL((tb_gemm<3>), dim3(64 * 8), dim3(256), 0, stream,
                       act, WmoutT, bm_out, nullptr, nullptr, fbuf, TOK, 1024, INNER_P, INNER_P, INNER_P, 1024);
    // ---- 10. rms over (N,D) per (b,h) ----
    hipLaunchKernelGGL(tb_rms_reduce, dim3(1024), dim3(256), 0, stream, fbuf, rms);
    // ---- 11. gate ----
    hipLaunchKernelGGL(tb_gate, dim3(TOK), dim3(256), 0, stream, x, W_g, b_g, gate);
    // ---- 12. o_final = o + gate*f/rms -> ob bf16 ----
    hipLaunchKernelGGL(tb_combine, dim3(TOK * 1024 / 4 / 256), dim3(256), 0, stream, obuf, fbuf, gate, rms, ob);
    // ---- 13. out = x + ob @ W_ao + b_ao ----
    hipLaunchKernelGGL((tb_gemm<1>), dim3(64 * 8), dim3(256), 0, stream,
                       ob, WaoT, b_ao, x, out, nullptr, TOK, 1024, 1024, 1024, 1024, 1024);
    // ---- 14a. sm = silu(xn @ W_f[:, 3072:] + b_f[3072:])  (bf16) ----
    hipLaunchKernelGGL((tb_gemm<5>), dim3(64 * 32), dim3(256), 0, stream,
                       xn, WfT + (size_t)3072 * 1024, b_f + 3072, nullptr, nullptr, sm,
                       TOK, 4096, 1024, 1024, 1024, 4096);
    // ---- 14b. out += sm @ W_mo + b_mo ----
    hipLaunchKernelGGL((tb_gemm<1>), dim3(64 * 8), dim3(256), 0, stream,
                       sm, WmoT, b_mo, out, out, nullptr, TOK, 1024, 4096, 4096, 4096, 1024);
}